// Round 1
// baseline (158.338 us; speedup 1.0000x reference)
//
#include <hip/hip_runtime.h>

#define N_ROIS 32768
#define N_GT   1024
#define BLOCK  64

__global__ __launch_bounds__(BLOCK) void roi_target_kernel(
    const float* __restrict__ rois,       // (N_ROIS, 5)
    const int*   __restrict__ roi_b,      // (N_ROIS,)
    const float* __restrict__ gt_boxes,   // (N_GT, 5)
    const int*   __restrict__ gt_b,       // (N_GT,)
    float*       __restrict__ out)        // labels[N_ROIS] ++ deltas[N_ROIS*4] ++ bbwgts[N_ROIS*4]
{
    __shared__ float s_x1[N_GT], s_y1[N_GT], s_x2[N_GT], s_y2[N_GT];
    __shared__ float s_area[N_GT], s_lab[N_GT];
    __shared__ int   s_b[N_GT];

    // Stage GT boxes into LDS. 64 threads x 16 iterations.
    for (int j = threadIdx.x; j < N_GT; j += BLOCK) {
        float x1 = gt_boxes[j * 5 + 0];
        float y1 = gt_boxes[j * 5 + 1];
        float x2 = gt_boxes[j * 5 + 2];
        float y2 = gt_boxes[j * 5 + 3];
        s_x1[j] = x1; s_y1[j] = y1; s_x2[j] = x2; s_y2[j] = y2;
        // Match numpy f32 op order: ((x2-x1)+1) * ((y2-y1)+1); adds feed mul, no
        // contraction hazard here.
        s_area[j] = __fmul_rn(__fadd_rn(__fsub_rn(x2, x1), 1.0f),
                              __fadd_rn(__fsub_rn(y2, y1), 1.0f));
        s_lab[j]  = gt_boxes[j * 5 + 4];
        s_b[j]    = gt_b[j];
    }
    __syncthreads();

    int i = blockIdx.x * BLOCK + threadIdx.x;   // one thread per ROI; grid exact
    float rx1 = rois[i * 5 + 0];
    float ry1 = rois[i * 5 + 1];
    float rx2 = rois[i * 5 + 2];
    float ry2 = rois[i * 5 + 3];
    int   rb  = roi_b[i];
    float area_r = __fmul_rn(__fadd_rn(__fsub_rn(rx2, rx1), 1.0f),
                             __fadd_rn(__fsub_rn(ry2, ry1), 1.0f));

    // Argmax scan over all GT. Strict > keeps FIRST max (numpy argmax semantics).
    float best = -2.0f;
    int   bj   = 0;
    for (int j = 0; j < N_GT; ++j) {
        float ix1 = fmaxf(rx1, s_x1[j]);
        float iy1 = fmaxf(ry1, s_y1[j]);
        float ix2 = fminf(rx2, s_x2[j]);
        float iy2 = fminf(ry2, s_y2[j]);
        float iw  = fmaxf(__fadd_rn(__fsub_rn(ix2, ix1), 1.0f), 0.0f);
        float ih  = fmaxf(__fadd_rn(__fsub_rn(iy2, iy1), 1.0f), 0.0f);
        float inter = __fmul_rn(iw, ih);
        // union = (area_r + area_g) - inter, with contraction blocked so the
        // product `inter` is rounded before the subtract (matches numpy).
        float uni = __fsub_rn(__fadd_rn(area_r, s_area[j]), inter);
        float v   = __fdiv_rn(inter, uni);
        v = (s_b[j] == rb) ? v : -1.0f;
        if (v > best) { best = v; bj = j; }
    }

    bool  fg    = (best >= 0.5f);
    float label = fg ? s_lab[bj] : 0.0f;   // gt labels are integral 1..80, exact in f32

    // Epilogue: bbox regression deltas, numpy f32 op order.
    float gx1 = s_x1[bj], gy1 = s_y1[bj], gx2 = s_x2[bj], gy2 = s_y2[bj];
    float ew  = __fadd_rn(__fsub_rn(rx2, rx1), 1.0f);
    float eh  = __fadd_rn(__fsub_rn(ry2, ry1), 1.0f);
    float ecx = __fadd_rn(rx1, __fmul_rn(0.5f, ew));   // 0.5*w exact; add rounded
    float ecy = __fadd_rn(ry1, __fmul_rn(0.5f, eh));
    float gw  = __fadd_rn(__fsub_rn(gx2, gx1), 1.0f);
    float gh  = __fadd_rn(__fsub_rn(gy2, gy1), 1.0f);
    float gcx = __fadd_rn(gx1, __fmul_rn(0.5f, gw));
    float gcy = __fadd_rn(gy1, __fmul_rn(0.5f, gh));

    float dx = __fdiv_rn(__fsub_rn(gcx, ecx), ew);
    float dy = __fdiv_rn(__fsub_rn(gcy, ecy), eh);
    float dw = logf(__fdiv_rn(gw, ew));
    float dh = logf(__fdiv_rn(gh, eh));

    if (!fg) { dx = 0.0f; dy = 0.0f; dw = 0.0f; dh = 0.0f; }
    float wgt = fg ? 1.0f : 0.0f;

    out[i] = label;
    float* dout = out + N_ROIS + i * 4;
    dout[0] = dx; dout[1] = dy; dout[2] = dw; dout[3] = dh;
    float* wout = out + N_ROIS + 4 * N_ROIS + i * 4;
    wout[0] = wgt; wout[1] = wgt; wout[2] = wgt; wout[3] = wgt;
}

extern "C" void kernel_launch(void* const* d_in, const int* in_sizes, int n_in,
                              void* d_out, int out_size, void* d_ws, size_t ws_size,
                              hipStream_t stream) {
    const float* rois  = (const float*)d_in[0];   // (32768,5)
    const int*   roi_b = (const int*)d_in[1];     // (32768,)
    const float* gt    = (const float*)d_in[2];   // (1024,5)
    const int*   gt_b  = (const int*)d_in[3];     // (1024,)
    float*       out   = (float*)d_out;           // 32768*9 floats

    roi_target_kernel<<<N_ROIS / BLOCK, BLOCK, 0, stream>>>(rois, roi_b, gt, gt_b, out);
}

// Round 2
// 87.482 us; speedup vs baseline: 1.8100x; 1.8100x over previous
//
#include <hip/hip_runtime.h>

#define N_ROIS 32768
#define N_GT   1024
#define BLOCK  256
#define CHUNKS 16                         // threads cooperating per ROI
#define ROIS_PER_BLOCK (BLOCK / CHUNKS)   // 16
#define ITERS (N_GT / CHUNKS)             // 64

__global__ __launch_bounds__(BLOCK) void roi_target_kernel(
    const float* __restrict__ rois,       // (N_ROIS, 5)
    const int*   __restrict__ roi_b,      // (N_ROIS,)
    const float* __restrict__ gt_boxes,   // (N_GT, 5)
    const int*   __restrict__ gt_b,       // (N_GT,)
    float*       __restrict__ out)        // labels[N_ROIS] ++ deltas[N_ROIS*4] ++ bbwgts[N_ROIS*4]
{
    __shared__ float4 s_box[N_GT];        // 16 KB  (x1,y1,x2,y2)
    __shared__ float  s_area[N_GT];       //  4 KB
    __shared__ int    s_meta[N_GT];       //  4 KB  (label<<3 | batch)

    // Stage GT boxes into LDS. 256 threads x 4 iterations.
    for (int j = threadIdx.x; j < N_GT; j += BLOCK) {
        float x1 = gt_boxes[j * 5 + 0];
        float y1 = gt_boxes[j * 5 + 1];
        float x2 = gt_boxes[j * 5 + 2];
        float y2 = gt_boxes[j * 5 + 3];
        s_box[j] = make_float4(x1, y1, x2, y2);
        // numpy f32 op order: ((x2-x1)+1) * ((y2-y1)+1)
        s_area[j] = __fmul_rn(__fadd_rn(__fsub_rn(x2, x1), 1.0f),
                              __fadd_rn(__fsub_rn(y2, y1), 1.0f));
        int lab = (int)gt_boxes[j * 5 + 4];   // integral 1..80, exact
        s_meta[j] = (lab << 3) | gt_b[j];     // batch 0..7
    }
    __syncthreads();

    int c   = threadIdx.x & (CHUNKS - 1);                     // GT chunk lane
    int roi = blockIdx.x * ROIS_PER_BLOCK + (threadIdx.x >> 4);

    float rx1 = rois[roi * 5 + 0];
    float ry1 = rois[roi * 5 + 1];
    float rx2 = rois[roi * 5 + 2];
    float ry2 = rois[roi * 5 + 3];
    int   rb  = roi_b[roi];
    float area_r = __fmul_rn(__fadd_rn(__fsub_rn(rx2, rx1), 1.0f),
                             __fadd_rn(__fsub_rn(ry2, ry1), 1.0f));

    // Partial argmax over j = c, c+16, ..., c+1008. Strict > keeps the
    // smallest j within this lane's (increasing) sequence.
    float best = -2.0f;
    int   bj   = c;
    #pragma unroll 4
    for (int it = 0; it < ITERS; ++it) {
        int j = it * CHUNKS + c;
        float4 b  = s_box[j];
        int  meta = s_meta[j];
        float ix1 = fmaxf(rx1, b.x);
        float iy1 = fmaxf(ry1, b.y);
        float ix2 = fminf(rx2, b.z);
        float iy2 = fminf(ry2, b.w);
        float iw  = fmaxf(__fadd_rn(__fsub_rn(ix2, ix1), 1.0f), 0.0f);
        float ih  = fmaxf(__fadd_rn(__fsub_rn(iy2, iy1), 1.0f), 0.0f);
        float inter = __fmul_rn(iw, ih);
        // union = (area_r + area_g) - inter; contraction blocked (matches numpy)
        float uni = __fsub_rn(__fadd_rn(area_r, s_area[j]), inter);
        float v   = __fdiv_rn(inter, uni);
        v = ((meta & 7) == rb) ? v : -1.0f;
        if (v > best) { best = v; bj = j; }
    }

    // Cross-chunk reduction within the 16-lane group. Equal value -> smaller j
    // wins, reproducing numpy argmax-first across the full 0..1023 range.
    #pragma unroll
    for (int m = 1; m < CHUNKS; m <<= 1) {
        float vo = __shfl_xor(best, m, 64);
        int   jo = __shfl_xor(bj,   m, 64);
        if (vo > best || (vo == best && jo < bj)) { best = vo; bj = jo; }
    }

    if (c == 0) {
        bool  fg    = (best >= 0.5f);
        float label = fg ? (float)(s_meta[bj] >> 3) : 0.0f;

        float4 g  = s_box[bj];
        float ew  = __fadd_rn(__fsub_rn(rx2, rx1), 1.0f);
        float eh  = __fadd_rn(__fsub_rn(ry2, ry1), 1.0f);
        float ecx = __fadd_rn(rx1, __fmul_rn(0.5f, ew));
        float ecy = __fadd_rn(ry1, __fmul_rn(0.5f, eh));
        float gw  = __fadd_rn(__fsub_rn(g.z, g.x), 1.0f);
        float gh  = __fadd_rn(__fsub_rn(g.w, g.y), 1.0f);
        float gcx = __fadd_rn(g.x, __fmul_rn(0.5f, gw));
        float gcy = __fadd_rn(g.y, __fmul_rn(0.5f, gh));

        float dx = __fdiv_rn(__fsub_rn(gcx, ecx), ew);
        float dy = __fdiv_rn(__fsub_rn(gcy, ecy), eh);
        float dw = logf(__fdiv_rn(gw, ew));
        float dh = logf(__fdiv_rn(gh, eh));

        if (!fg) { dx = 0.0f; dy = 0.0f; dw = 0.0f; dh = 0.0f; }
        float wgt = fg ? 1.0f : 0.0f;

        out[roi] = label;
        float* dout = out + N_ROIS + roi * 4;
        dout[0] = dx; dout[1] = dy; dout[2] = dw; dout[3] = dh;
        float* wout = out + N_ROIS + 4 * N_ROIS + roi * 4;
        wout[0] = wgt; wout[1] = wgt; wout[2] = wgt; wout[3] = wgt;
    }
}

extern "C" void kernel_launch(void* const* d_in, const int* in_sizes, int n_in,
                              void* d_out, int out_size, void* d_ws, size_t ws_size,
                              hipStream_t stream) {
    const float* rois  = (const float*)d_in[0];   // (32768,5)
    const int*   roi_b = (const int*)d_in[1];     // (32768,)
    const float* gt    = (const float*)d_in[2];   // (1024,5)
    const int*   gt_b  = (const int*)d_in[3];     // (1024,)
    float*       out   = (float*)d_out;           // 32768*9 floats

    roi_target_kernel<<<N_ROIS / ROIS_PER_BLOCK, BLOCK, 0, stream>>>(
        rois, roi_b, gt, gt_b, out);
}

// Round 3
// 77.392 us; speedup vs baseline: 2.0459x; 1.1304x over previous
//
#include <hip/hip_runtime.h>

#define N_ROIS 32768
#define N_GT   1024
#define N_IMG  8
#define BLOCK  256
#define CHUNKS 16                         // lanes cooperating per ROI
#define ROIS_PER_BLOCK (BLOCK / CHUNKS)   // 16

// d_ws layout (floats):
//   [0    .. 4095]  sorted gt box float4 (x1,y1,x2,y2)
//   [4096 .. 5119]  sorted gt area
//   [5120 .. 6143]  sorted gt original index (int bits)
//   [6144 .. 6152]  segment bounds seg[0..8] (int bits)
#define WS_BOX  0
#define WS_AREA 4096
#define WS_OJ   5120
#define WS_SEG  6144

// ---------------------------------------------------------------------------
// Pre-kernel: stable counting sort of GT boxes by batch index. 1 block x 64.
// Stability (original-index order within each batch) is REQUIRED to reproduce
// numpy argmax first-index tie-break semantics.
// ---------------------------------------------------------------------------
__global__ __launch_bounds__(64) void gt_sort_kernel(
    const float* __restrict__ gt_boxes,   // (N_GT, 5)
    const int*   __restrict__ gt_b,       // (N_GT,)
    float*       __restrict__ ws)
{
    __shared__ int sb[N_GT];              // batch per gt
    __shared__ int chist[16][N_IMG];      // per-chunk per-batch counts -> bases
    __shared__ int seg[N_IMG + 1];

    int lane = threadIdx.x;
    unsigned long long lt_mask = (lane == 63) ? 0xFFFFFFFFFFFFFFFFull >> 1
                                              : ((1ull << lane) - 1ull);

    for (int chunk = 0; chunk < 16; ++chunk)
        sb[chunk * 64 + lane] = gt_b[chunk * 64 + lane];
    __syncthreads();

    // per-chunk histograms via wave ballots (block == one wave, no divergence)
    for (int chunk = 0; chunk < 16; ++chunk) {
        int b = sb[chunk * 64 + lane];
        for (int bb = 0; bb < N_IMG; ++bb) {
            unsigned long long m = __ballot(b == bb);
            if (lane == bb) chist[chunk][bb] = __popcll(m);
        }
    }
    __syncthreads();

    if (lane == 0) {
        int tot[N_IMG];
        for (int b = 0; b < N_IMG; ++b) {
            int s = 0;
            for (int c = 0; c < 16; ++c) s += chist[c][b];
            tot[b] = s;
        }
        int base = 0;
        for (int b = 0; b < N_IMG; ++b) {
            seg[b] = base;
            int run = base;
            for (int c = 0; c < 16; ++c) {
                int t = chist[c][b];
                chist[c][b] = run;          // becomes chunk base
                run += t;
            }
            base += tot[b];
        }
        seg[N_IMG] = N_GT;
        int* wseg = (int*)(ws + WS_SEG);
        for (int b = 0; b <= N_IMG; ++b) wseg[b] = seg[b];
    }
    __syncthreads();

    // stable scatter
    float4* wbox = (float4*)(ws + WS_BOX);
    float*  warea = ws + WS_AREA;
    int*    woj   = (int*)(ws + WS_OJ);
    for (int chunk = 0; chunk < 16; ++chunk) {
        int j = chunk * 64 + lane;
        int b = sb[j];
        unsigned long long mym = 0;
        for (int bb = 0; bb < N_IMG; ++bb) {
            unsigned long long m = __ballot(b == bb);
            if (b == bb) mym = m;
        }
        int rank = chist[chunk][b] + __popcll(mym & lt_mask);
        float x1 = gt_boxes[j * 5 + 0];
        float y1 = gt_boxes[j * 5 + 1];
        float x2 = gt_boxes[j * 5 + 2];
        float y2 = gt_boxes[j * 5 + 3];
        wbox[rank]  = make_float4(x1, y1, x2, y2);
        // numpy f32 op order: ((x2-x1)+1) * ((y2-y1)+1)
        warea[rank] = __fmul_rn(__fadd_rn(__fsub_rn(x2, x1), 1.0f),
                                __fadd_rn(__fsub_rn(y2, y1), 1.0f));
        woj[rank]   = j;
    }
}

// ---------------------------------------------------------------------------
// Main kernel: 16 lanes per ROI scan only the ROI's batch segment (~128 GT).
// ---------------------------------------------------------------------------
__global__ __launch_bounds__(BLOCK) void roi_target_kernel(
    const float* __restrict__ rois,       // (N_ROIS, 5)
    const int*   __restrict__ roi_b,      // (N_ROIS,)
    const float* __restrict__ gt_boxes,   // (N_GT, 5) -- labels in epilogue
    const float* __restrict__ ws,
    float*       __restrict__ out)        // labels ++ deltas ++ bbwgts
{
    __shared__ float4 s_box[N_GT];        // 16 KB sorted
    __shared__ float  s_area[N_GT];       //  4 KB
    __shared__ int    s_oj[N_GT];         //  4 KB original index
    __shared__ int    s_seg[N_IMG + 1];

    const float4* wbox  = (const float4*)(ws + WS_BOX);
    const float*  warea = ws + WS_AREA;
    const int*    woj   = (const int*)(ws + WS_OJ);
    const int*    wseg  = (const int*)(ws + WS_SEG);

    for (int t = threadIdx.x; t < N_GT; t += BLOCK) {
        s_box[t]  = wbox[t];
        s_area[t] = warea[t];
        s_oj[t]   = woj[t];
    }
    if (threadIdx.x <= N_IMG) s_seg[threadIdx.x] = wseg[threadIdx.x];
    __syncthreads();

    int c   = threadIdx.x & (CHUNKS - 1);
    int roi = blockIdx.x * ROIS_PER_BLOCK + (threadIdx.x >> 4);

    float rx1 = rois[roi * 5 + 0];
    float ry1 = rois[roi * 5 + 1];
    float rx2 = rois[roi * 5 + 2];
    float ry2 = rois[roi * 5 + 3];
    int   rb  = roi_b[roi];
    float area_r = __fmul_rn(__fadd_rn(__fsub_rn(rx2, rx1), 1.0f),
                             __fadd_rn(__fsub_rn(ry2, ry1), 1.0f));

    int st = s_seg[rb];
    int en = s_seg[rb + 1];

    // Scan this batch's segment; positions increasing per lane, so strict >
    // keeps the first max. Within a batch, position order == original-j order.
    float best = -2.0f;
    int   bp   = -1;
    for (int p = st + c; p < en; p += CHUNKS) {
        float4 b  = s_box[p];
        float ix1 = fmaxf(rx1, b.x);
        float iy1 = fmaxf(ry1, b.y);
        float ix2 = fminf(rx2, b.z);
        float iy2 = fminf(ry2, b.w);
        float iw  = fmaxf(__fadd_rn(__fsub_rn(ix2, ix1), 1.0f), 0.0f);
        float ih  = fmaxf(__fadd_rn(__fsub_rn(iy2, iy1), 1.0f), 0.0f);
        float inter = __fmul_rn(iw, ih);
        // union = (area_r + area_g) - inter; contraction blocked (matches numpy)
        float uni = __fsub_rn(__fadd_rn(area_r, s_area[p]), inter);
        float v   = __fdiv_rn(inter, uni);
        if (v > best) { best = v; bp = p; }
    }

    // Cross-lane reduce over the 16-lane group; equal value -> smaller
    // position wins (== smaller original j within the batch).
    #pragma unroll
    for (int m = 1; m < CHUNKS; m <<= 1) {
        float vo = __shfl_xor(best, m, 64);
        int   po = __shfl_xor(bp,   m, 64);
        if (vo > best || (vo == best && po < bp)) { best = vo; bp = po; }
    }

    if (c == 0) {
        bool fg = (best >= 0.5f);          // best is bit-exact numpy max (or -2 -> false)
        int  pp = (bp < 0) ? st : bp;      // safe index; outputs zeroed when !fg

        float label = 0.0f;
        if (fg) label = gt_boxes[s_oj[pp] * 5 + 4];   // integral 1..80

        float4 g  = s_box[pp];
        float ew  = __fadd_rn(__fsub_rn(rx2, rx1), 1.0f);
        float eh  = __fadd_rn(__fsub_rn(ry2, ry1), 1.0f);
        float ecx = __fadd_rn(rx1, __fmul_rn(0.5f, ew));
        float ecy = __fadd_rn(ry1, __fmul_rn(0.5f, eh));
        float gw  = __fadd_rn(__fsub_rn(g.z, g.x), 1.0f);
        float gh  = __fadd_rn(__fsub_rn(g.w, g.y), 1.0f);
        float gcx = __fadd_rn(g.x, __fmul_rn(0.5f, gw));
        float gcy = __fadd_rn(g.y, __fmul_rn(0.5f, gh));

        float dx = __fdiv_rn(__fsub_rn(gcx, ecx), ew);
        float dy = __fdiv_rn(__fsub_rn(gcy, ecy), eh);
        float dw = logf(__fdiv_rn(gw, ew));
        float dh = logf(__fdiv_rn(gh, eh));

        if (!fg) { dx = 0.0f; dy = 0.0f; dw = 0.0f; dh = 0.0f; }
        float wgt = fg ? 1.0f : 0.0f;

        out[roi] = label;
        float* dout = out + N_ROIS + roi * 4;
        dout[0] = dx; dout[1] = dy; dout[2] = dw; dout[3] = dh;
        float* wout = out + N_ROIS + 4 * N_ROIS + roi * 4;
        wout[0] = wgt; wout[1] = wgt; wout[2] = wgt; wout[3] = wgt;
    }
}

extern "C" void kernel_launch(void* const* d_in, const int* in_sizes, int n_in,
                              void* d_out, int out_size, void* d_ws, size_t ws_size,
                              hipStream_t stream) {
    const float* rois  = (const float*)d_in[0];   // (32768,5)
    const int*   roi_b = (const int*)d_in[1];     // (32768,)
    const float* gt    = (const float*)d_in[2];   // (1024,5)
    const int*   gt_b  = (const int*)d_in[3];     // (1024,)
    float*       ws    = (float*)d_ws;
    float*       out   = (float*)d_out;           // 32768*9 floats

    gt_sort_kernel<<<1, 64, 0, stream>>>(gt, gt_b, ws);
    roi_target_kernel<<<N_ROIS / ROIS_PER_BLOCK, BLOCK, 0, stream>>>(
        rois, roi_b, gt, ws, out);
}

// Round 4
// 73.837 us; speedup vs baseline: 2.1444x; 1.0481x over previous
//
#include <hip/hip_runtime.h>

#define N_ROIS 32768
#define N_GT   1024
#define N_IMG  8
#define BLOCK  256
#define CHUNKS 16                         // lanes cooperating per ROI
#define ROIS_PER_BLOCK (BLOCK / CHUNKS)   // 16

// d_ws layout (floats):
//   [0    .. 4095]  sorted gt box float4 (x1,y1,x2,y2)
//   [4096 .. 5119]  sorted gt area
//   [5120 .. 6143]  sorted gt original index (int bits)
//   [6144 .. 6152]  segment bounds seg[0..8] (int bits)
#define WS_BOX  0
#define WS_AREA 4096
#define WS_OJ   5120
#define WS_SEG  6144

// ---------------------------------------------------------------------------
// Pre-kernel: stable counting sort of GT boxes by batch index. 1 block x 64.
// v2: the cross-chunk prefix is a parallel in-register shfl scan — the v1
// lane-0 serial LDS chain (~256 dependent ~120cyc accesses ≈ 15 µs of whole-
// GPU idle) is eliminated.
// ---------------------------------------------------------------------------
__global__ __launch_bounds__(64) void gt_sort_kernel(
    const float* __restrict__ gt_boxes,   // (N_GT, 5)
    const int*   __restrict__ gt_b,       // (N_GT,)
    float*       __restrict__ ws)
{
    __shared__ int s_cbase[16][N_IMG];    // global base per (chunk, batch)

    int lane = threadIdx.x;
    unsigned long long lt_mask = (lane == 63) ? (~0ull >> 1)
                                              : ((1ull << lane) - 1ull);

    int myc    = lane & 15;               // chunk this lane tallies
    int myb_lo = lane >> 4;               // batches this lane tallies (2 of 8)
    int myb_hi = myb_lo + 4;

    int bvals[16];                        // this lane's gt batch, per chunk
    int rankc[16];                        // rank within (chunk, batch)
    int cnt_lo = 0, cnt_hi = 0;           // hist cells owned by this lane

    #pragma unroll
    for (int chunk = 0; chunk < 16; ++chunk) {
        int b = gt_b[chunk * 64 + lane];
        bvals[chunk] = b;
        unsigned long long mym = 0;
        #pragma unroll
        for (int bb = 0; bb < N_IMG; ++bb) {
            unsigned long long m = __ballot(b == bb);   // wave-uniform result
            if (b == bb) mym = m;
            int pc = __popcll(m);
            if (chunk == myc && bb == myb_lo) cnt_lo = pc;
            if (chunk == myc && bb == myb_hi) cnt_hi = pc;
        }
        rankc[chunk] = __popcll(mym & lt_mask);
    }

    // Inclusive scan over chunks within each 16-lane group (2 batch slots).
    int inc_lo = cnt_lo, inc_hi = cnt_hi;
    #pragma unroll
    for (int d = 1; d < 16; d <<= 1) {
        int t_lo = __shfl_up(inc_lo, d, 16);
        int t_hi = __shfl_up(inc_hi, d, 16);
        if (myc >= d) { inc_lo += t_lo; inc_hi += t_hi; }
    }
    // Batch totals live at chunk-15 lanes of each group; broadcast wave-wide.
    int t0 = __shfl(inc_lo, 15, 64);      // batch 0 (group 0, lane 15)
    int t1 = __shfl(inc_lo, 31, 64);      // batch 1
    int t2 = __shfl(inc_lo, 47, 64);      // batch 2
    int t3 = __shfl(inc_lo, 63, 64);      // batch 3
    int t4 = __shfl(inc_hi, 15, 64);      // batch 4
    int t5 = __shfl(inc_hi, 31, 64);      // batch 5
    int t6 = __shfl(inc_hi, 47, 64);      // batch 6
    int t7 = __shfl(inc_hi, 63, 64);      // batch 7

    int seg[N_IMG + 1];
    seg[0] = 0;
    seg[1] = seg[0] + t0;  seg[2] = seg[1] + t1;
    seg[3] = seg[2] + t2;  seg[4] = seg[3] + t3;
    seg[5] = seg[4] + t4;  seg[6] = seg[5] + t5;
    seg[7] = seg[6] + t6;  seg[8] = seg[7] + t7;   // == N_GT

    if (lane <= N_IMG) ((int*)(ws + WS_SEG))[lane] = seg[lane];

    // chunk base = seg[b] + (exclusive chunk prefix) for the 2 owned cells.
    s_cbase[myc][myb_lo] = seg[myb_lo] + (inc_lo - cnt_lo);
    s_cbase[myc][myb_hi] = seg[myb_hi] + (inc_hi - cnt_hi);
    __syncthreads();

    // Stable scatter (fully parallel).
    float4* wbox  = (float4*)(ws + WS_BOX);
    float*  warea = ws + WS_AREA;
    int*    woj   = (int*)(ws + WS_OJ);
    #pragma unroll
    for (int chunk = 0; chunk < 16; ++chunk) {
        int j = chunk * 64 + lane;
        int b = bvals[chunk];
        int rank = s_cbase[chunk][b] + rankc[chunk];
        float x1 = gt_boxes[j * 5 + 0];
        float y1 = gt_boxes[j * 5 + 1];
        float x2 = gt_boxes[j * 5 + 2];
        float y2 = gt_boxes[j * 5 + 3];
        wbox[rank]  = make_float4(x1, y1, x2, y2);
        // numpy f32 op order: ((x2-x1)+1) * ((y2-y1)+1)
        warea[rank] = __fmul_rn(__fadd_rn(__fsub_rn(x2, x1), 1.0f),
                                __fadd_rn(__fsub_rn(y2, y1), 1.0f));
        woj[rank]   = j;
    }
}

// ---------------------------------------------------------------------------
// Main kernel: 16 lanes per ROI scan only the ROI's batch segment (~128 GT).
// ---------------------------------------------------------------------------
__global__ __launch_bounds__(BLOCK) void roi_target_kernel(
    const float* __restrict__ rois,       // (N_ROIS, 5)
    const int*   __restrict__ roi_b,      // (N_ROIS,)
    const float* __restrict__ gt_boxes,   // (N_GT, 5) -- labels in epilogue
    const float* __restrict__ ws,
    float*       __restrict__ out)        // labels ++ deltas ++ bbwgts
{
    __shared__ float4 s_box[N_GT];        // 16 KB sorted
    __shared__ float  s_area[N_GT];       //  4 KB
    __shared__ int    s_oj[N_GT];         //  4 KB original index
    __shared__ int    s_seg[N_IMG + 1];

    const float4* wbox  = (const float4*)(ws + WS_BOX);
    const float*  warea = ws + WS_AREA;
    const int*    woj   = (const int*)(ws + WS_OJ);
    const int*    wseg  = (const int*)(ws + WS_SEG);

    for (int t = threadIdx.x; t < N_GT; t += BLOCK) {
        s_box[t]  = wbox[t];
        s_area[t] = warea[t];
        s_oj[t]   = woj[t];
    }
    if (threadIdx.x <= N_IMG) s_seg[threadIdx.x] = wseg[threadIdx.x];
    __syncthreads();

    int c   = threadIdx.x & (CHUNKS - 1);
    int roi = blockIdx.x * ROIS_PER_BLOCK + (threadIdx.x >> 4);

    float rx1 = rois[roi * 5 + 0];
    float ry1 = rois[roi * 5 + 1];
    float rx2 = rois[roi * 5 + 2];
    float ry2 = rois[roi * 5 + 3];
    int   rb  = roi_b[roi];
    float area_r = __fmul_rn(__fadd_rn(__fsub_rn(rx2, rx1), 1.0f),
                             __fadd_rn(__fsub_rn(ry2, ry1), 1.0f));

    int st = s_seg[rb];
    int en = s_seg[rb + 1];

    // Scan this batch's segment; positions increasing per lane, so strict >
    // keeps the first max. Within a batch, position order == original-j order.
    float best = -2.0f;
    int   bp   = -1;
    for (int p = st + c; p < en; p += CHUNKS) {
        float4 b  = s_box[p];
        float ix1 = fmaxf(rx1, b.x);
        float iy1 = fmaxf(ry1, b.y);
        float ix2 = fminf(rx2, b.z);
        float iy2 = fminf(ry2, b.w);
        float iw  = fmaxf(__fadd_rn(__fsub_rn(ix2, ix1), 1.0f), 0.0f);
        float ih  = fmaxf(__fadd_rn(__fsub_rn(iy2, iy1), 1.0f), 0.0f);
        float inter = __fmul_rn(iw, ih);
        // union = (area_r + area_g) - inter; contraction blocked (matches numpy)
        float uni = __fsub_rn(__fadd_rn(area_r, s_area[p]), inter);
        float v   = __fdiv_rn(inter, uni);
        if (v > best) { best = v; bp = p; }
    }

    // Cross-lane reduce over the 16-lane group; equal value -> smaller
    // position wins (== smaller original j within the batch).
    #pragma unroll
    for (int m = 1; m < CHUNKS; m <<= 1) {
        float vo = __shfl_xor(best, m, 64);
        int   po = __shfl_xor(bp,   m, 64);
        if (vo > best || (vo == best && po < bp)) { best = vo; bp = po; }
    }

    if (c == 0) {
        bool fg = (best >= 0.5f);          // best is bit-exact numpy max (or -2 -> false)
        int  pp = (bp < 0) ? 0 : bp;       // safe index; outputs zeroed when !fg

        float label = 0.0f;
        if (fg) label = gt_boxes[s_oj[pp] * 5 + 4];   // integral 1..80

        float4 g  = s_box[pp];
        float ew  = __fadd_rn(__fsub_rn(rx2, rx1), 1.0f);
        float eh  = __fadd_rn(__fsub_rn(ry2, ry1), 1.0f);
        float ecx = __fadd_rn(rx1, __fmul_rn(0.5f, ew));
        float ecy = __fadd_rn(ry1, __fmul_rn(0.5f, eh));
        float gw  = __fadd_rn(__fsub_rn(g.z, g.x), 1.0f);
        float gh  = __fadd_rn(__fsub_rn(g.w, g.y), 1.0f);
        float gcx = __fadd_rn(g.x, __fmul_rn(0.5f, gw));
        float gcy = __fadd_rn(g.y, __fmul_rn(0.5f, gh));

        float dx = __fdiv_rn(__fsub_rn(gcx, ecx), ew);
        float dy = __fdiv_rn(__fsub_rn(gcy, ecy), eh);
        float dw = logf(__fdiv_rn(gw, ew));
        float dh = logf(__fdiv_rn(gh, eh));

        if (!fg) { dx = 0.0f; dy = 0.0f; dw = 0.0f; dh = 0.0f; }
        float wgt = fg ? 1.0f : 0.0f;

        out[roi] = label;
        float* dout = out + N_ROIS + roi * 4;
        dout[0] = dx; dout[1] = dy; dout[2] = dw; dout[3] = dh;
        float* wout = out + N_ROIS + 4 * N_ROIS + roi * 4;
        wout[0] = wgt; wout[1] = wgt; wout[2] = wgt; wout[3] = wgt;
    }
}

extern "C" void kernel_launch(void* const* d_in, const int* in_sizes, int n_in,
                              void* d_out, int out_size, void* d_ws, size_t ws_size,
                              hipStream_t stream) {
    const float* rois  = (const float*)d_in[0];   // (32768,5)
    const int*   roi_b = (const int*)d_in[1];     // (32768,)
    const float* gt    = (const float*)d_in[2];   // (1024,5)
    const int*   gt_b  = (const int*)d_in[3];     // (1024,)
    float*       ws    = (float*)d_ws;
    float*       out   = (float*)d_out;           // 32768*9 floats

    gt_sort_kernel<<<1, 64, 0, stream>>>(gt, gt_b, ws);
    roi_target_kernel<<<N_ROIS / ROIS_PER_BLOCK, BLOCK, 0, stream>>>(
        rois, roi_b, gt, ws, out);
}

// Round 5
// 72.297 us; speedup vs baseline: 2.1901x; 1.0213x over previous
//
#include <hip/hip_runtime.h>

#define N_ROIS 32768
#define N_GT   1024
#define N_IMG  8
#define BLOCK  256
#define CHUNKS 16                         // lanes cooperating per ROI (main kernel)
#define ROIS_PER_BLOCK (BLOCK / CHUNKS)   // 16

// d_ws layout (floats):
//   [0    .. 4095]  sorted gt box float4 (x1,y1,x2,y2)
//   [4096 .. 5119]  sorted gt area
//   [5120 .. 6143]  sorted gt original index (int bits)
//   [6144 .. 6152]  segment bounds seg[0..8] (int bits)
#define WS_BOX  0
#define WS_AREA 4096
#define WS_OJ   5120
#define WS_SEG  6144

// ---------------------------------------------------------------------------
// Pre-kernel: stable counting sort of GT boxes by batch index. 1 block x 256
// (4 waves). v3: ALL global loads are prefetched into registers up front
// (phase 0) — v2 serialized ~80 cold-HBM round-trips (~1300 cyc each = 42 µs,
// VALUBusy 0.005%). Wave w owns chunks 4w..4w+3; ballot pattern per chunk is
// identical to v1/v2, so ranks and sorted order are bit-identical.
// ---------------------------------------------------------------------------
__global__ __launch_bounds__(256) void gt_sort_kernel(
    const float* __restrict__ gt_boxes,   // (N_GT, 5)
    const int*   __restrict__ gt_b,       // (N_GT,)
    float*       __restrict__ ws)
{
    __shared__ int s_chist[16][N_IMG];    // counts per (chunk, batch)
    __shared__ int s_cbase[16][N_IMG];    // global base per (chunk, batch)

    int tid  = threadIdx.x;
    int lane = tid & 63;
    int wave = tid >> 6;                  // 0..3; owns chunks 4w..4w+3

    unsigned long long lt_mask = (lane == 63) ? (~0ull >> 1)
                                              : ((1ull << lane) - 1ull);

    // ---- Phase 0: prefetch everything (20 independent loads, one round-trip)
    int   bv[4];
    float bx1[4], by1[4], bx2[4], by2[4];
    #pragma unroll
    for (int k = 0; k < 4; ++k) {
        int j = (wave * 4 + k) * 64 + lane;
        bv[k]  = gt_b[j];
        bx1[k] = gt_boxes[j * 5 + 0];
        by1[k] = gt_boxes[j * 5 + 1];
        bx2[k] = gt_boxes[j * 5 + 2];
        by2[k] = gt_boxes[j * 5 + 3];
    }

    // ---- Phase 1: per-chunk histograms + stable in-chunk ranks via ballots
    int rankc[4];
    #pragma unroll
    for (int k = 0; k < 4; ++k) {
        int b = bv[k];
        unsigned long long mym = 0;
        #pragma unroll
        for (int bb = 0; bb < N_IMG; ++bb) {
            unsigned long long m = __ballot(b == bb);
            if (b == bb) mym = m;
            if (lane == bb) s_chist[wave * 4 + k][bb] = __popcll(m);
        }
        rankc[k] = __popcll(mym & lt_mask);
    }
    __syncthreads();

    // ---- Phase 2: wave 0 computes chunk bases via in-register shfl scan
    if (wave == 0) {
        int myc    = lane & 15;           // chunk
        int myb_lo = lane >> 4;           // batch (2 slots per lane)
        int myb_hi = myb_lo + 4;
        int cnt_lo = s_chist[myc][myb_lo];
        int cnt_hi = s_chist[myc][myb_hi];
        int inc_lo = cnt_lo, inc_hi = cnt_hi;
        #pragma unroll
        for (int d = 1; d < 16; d <<= 1) {
            int t_lo = __shfl_up(inc_lo, d, 16);
            int t_hi = __shfl_up(inc_hi, d, 16);
            if (myc >= d) { inc_lo += t_lo; inc_hi += t_hi; }
        }
        int t0 = __shfl(inc_lo, 15, 64);
        int t1 = __shfl(inc_lo, 31, 64);
        int t2 = __shfl(inc_lo, 47, 64);
        int t3 = __shfl(inc_lo, 63, 64);
        int t4 = __shfl(inc_hi, 15, 64);
        int t5 = __shfl(inc_hi, 31, 64);
        int t6 = __shfl(inc_hi, 47, 64);
        int t7 = __shfl(inc_hi, 63, 64);

        int s0 = 0;
        int s1 = s0 + t0, s2 = s1 + t1, s3 = s2 + t2, s4 = s3 + t3;
        int s5 = s4 + t4, s6 = s5 + t5, s7 = s6 + t6, s8 = s7 + t7; // == N_GT

        if (lane == 0) {                  // unrolled scalar stores, no scratch
            int* wseg = (int*)(ws + WS_SEG);
            wseg[0] = s0; wseg[1] = s1; wseg[2] = s2; wseg[3] = s3;
            wseg[4] = s4; wseg[5] = s5; wseg[6] = s6; wseg[7] = s7;
            wseg[8] = s8;
        }
        int seg_lo = (myb_lo == 0) ? s0 : (myb_lo == 1) ? s1
                   : (myb_lo == 2) ? s2 : s3;
        int seg_hi = (myb_hi == 4) ? s4 : (myb_hi == 5) ? s5
                   : (myb_hi == 6) ? s6 : s7;
        s_cbase[myc][myb_lo] = seg_lo + (inc_lo - cnt_lo);
        s_cbase[myc][myb_hi] = seg_hi + (inc_hi - cnt_hi);
    }
    __syncthreads();

    // ---- Phase 3: stable scatter from prefetched registers (no new loads)
    float4* wbox  = (float4*)(ws + WS_BOX);
    float*  warea = ws + WS_AREA;
    int*    woj   = (int*)(ws + WS_OJ);
    #pragma unroll
    for (int k = 0; k < 4; ++k) {
        int chunk = wave * 4 + k;
        int j     = chunk * 64 + lane;
        int rank  = s_cbase[chunk][bv[k]] + rankc[k];
        wbox[rank]  = make_float4(bx1[k], by1[k], bx2[k], by2[k]);
        // numpy f32 op order: ((x2-x1)+1) * ((y2-y1)+1)
        warea[rank] = __fmul_rn(__fadd_rn(__fsub_rn(bx2[k], bx1[k]), 1.0f),
                                __fadd_rn(__fsub_rn(by2[k], by1[k]), 1.0f));
        woj[rank]   = j;
    }
}

// ---------------------------------------------------------------------------
// Main kernel: 16 lanes per ROI scan only the ROI's batch segment (~128 GT).
// ---------------------------------------------------------------------------
__global__ __launch_bounds__(BLOCK) void roi_target_kernel(
    const float* __restrict__ rois,       // (N_ROIS, 5)
    const int*   __restrict__ roi_b,      // (N_ROIS,)
    const float* __restrict__ gt_boxes,   // (N_GT, 5) -- labels in epilogue
    const float* __restrict__ ws,
    float*       __restrict__ out)        // labels ++ deltas ++ bbwgts
{
    __shared__ float4 s_box[N_GT];        // 16 KB sorted
    __shared__ float  s_area[N_GT];       //  4 KB
    __shared__ int    s_oj[N_GT];         //  4 KB original index
    __shared__ int    s_seg[N_IMG + 1];

    const float4* wbox  = (const float4*)(ws + WS_BOX);
    const float*  warea = ws + WS_AREA;
    const int*    woj   = (const int*)(ws + WS_OJ);
    const int*    wseg  = (const int*)(ws + WS_SEG);

    for (int t = threadIdx.x; t < N_GT; t += BLOCK) {
        s_box[t]  = wbox[t];
        s_area[t] = warea[t];
        s_oj[t]   = woj[t];
    }
    if (threadIdx.x <= N_IMG) s_seg[threadIdx.x] = wseg[threadIdx.x];
    __syncthreads();

    int c   = threadIdx.x & (CHUNKS - 1);
    int roi = blockIdx.x * ROIS_PER_BLOCK + (threadIdx.x >> 4);

    float rx1 = rois[roi * 5 + 0];
    float ry1 = rois[roi * 5 + 1];
    float rx2 = rois[roi * 5 + 2];
    float ry2 = rois[roi * 5 + 3];
    int   rb  = roi_b[roi];
    float area_r = __fmul_rn(__fadd_rn(__fsub_rn(rx2, rx1), 1.0f),
                             __fadd_rn(__fsub_rn(ry2, ry1), 1.0f));

    int st = s_seg[rb];
    int en = s_seg[rb + 1];

    // Scan this batch's segment; positions increasing per lane, so strict >
    // keeps the first max. Within a batch, position order == original-j order.
    float best = -2.0f;
    int   bp   = -1;
    for (int p = st + c; p < en; p += CHUNKS) {
        float4 b  = s_box[p];
        float ix1 = fmaxf(rx1, b.x);
        float iy1 = fmaxf(ry1, b.y);
        float ix2 = fminf(rx2, b.z);
        float iy2 = fminf(ry2, b.w);
        float iw  = fmaxf(__fadd_rn(__fsub_rn(ix2, ix1), 1.0f), 0.0f);
        float ih  = fmaxf(__fadd_rn(__fsub_rn(iy2, iy1), 1.0f), 0.0f);
        float inter = __fmul_rn(iw, ih);
        // union = (area_r + area_g) - inter; contraction blocked (matches numpy)
        float uni = __fsub_rn(__fadd_rn(area_r, s_area[p]), inter);
        float v   = __fdiv_rn(inter, uni);
        if (v > best) { best = v; bp = p; }
    }

    // Cross-lane reduce over the 16-lane group; equal value -> smaller
    // position wins (== smaller original j within the batch).
    #pragma unroll
    for (int m = 1; m < CHUNKS; m <<= 1) {
        float vo = __shfl_xor(best, m, 64);
        int   po = __shfl_xor(bp,   m, 64);
        if (vo > best || (vo == best && po < bp)) { best = vo; bp = po; }
    }

    if (c == 0) {
        bool fg = (best >= 0.5f);          // best is bit-exact numpy max (or -2 -> false)
        int  pp = (bp < 0) ? 0 : bp;       // safe index; outputs zeroed when !fg

        float label = 0.0f;
        if (fg) label = gt_boxes[s_oj[pp] * 5 + 4];   // integral 1..80

        float4 g  = s_box[pp];
        float ew  = __fadd_rn(__fsub_rn(rx2, rx1), 1.0f);
        float eh  = __fadd_rn(__fsub_rn(ry2, ry1), 1.0f);
        float ecx = __fadd_rn(rx1, __fmul_rn(0.5f, ew));
        float ecy = __fadd_rn(ry1, __fmul_rn(0.5f, eh));
        float gw  = __fadd_rn(__fsub_rn(g.z, g.x), 1.0f);
        float gh  = __fadd_rn(__fsub_rn(g.w, g.y), 1.0f);
        float gcx = __fadd_rn(g.x, __fmul_rn(0.5f, gw));
        float gcy = __fadd_rn(g.y, __fmul_rn(0.5f, gh));

        float dx = __fdiv_rn(__fsub_rn(gcx, ecx), ew);
        float dy = __fdiv_rn(__fsub_rn(gcy, ecy), eh);
        float dw = logf(__fdiv_rn(gw, ew));
        float dh = logf(__fdiv_rn(gh, eh));

        if (!fg) { dx = 0.0f; dy = 0.0f; dw = 0.0f; dh = 0.0f; }
        float wgt = fg ? 1.0f : 0.0f;

        out[roi] = label;
        float* dout = out + N_ROIS + roi * 4;
        dout[0] = dx; dout[1] = dy; dout[2] = dw; dout[3] = dh;
        float* wout = out + N_ROIS + 4 * N_ROIS + roi * 4;
        wout[0] = wgt; wout[1] = wgt; wout[2] = wgt; wout[3] = wgt;
    }
}

extern "C" void kernel_launch(void* const* d_in, const int* in_sizes, int n_in,
                              void* d_out, int out_size, void* d_ws, size_t ws_size,
                              hipStream_t stream) {
    const float* rois  = (const float*)d_in[0];   // (32768,5)
    const int*   roi_b = (const int*)d_in[1];     // (32768,)
    const float* gt    = (const float*)d_in[2];   // (1024,5)
    const int*   gt_b  = (const int*)d_in[3];     // (1024,)
    float*       ws    = (float*)d_ws;
    float*       out   = (float*)d_out;           // 32768*9 floats

    gt_sort_kernel<<<1, 256, 0, stream>>>(gt, gt_b, ws);
    roi_target_kernel<<<N_ROIS / ROIS_PER_BLOCK, BLOCK, 0, stream>>>(
        rois, roi_b, gt, ws, out);
}